// Round 9
// baseline (612.484 us; speedup 1.0000x reference)
//
#include <hip/hip_runtime.h>
#include <cstdio>

typedef unsigned short u16;
typedef unsigned int u32;
typedef __attribute__((ext_vector_type(8))) short bf16x8;
typedef __attribute__((ext_vector_type(4))) float f32x4;

static constexpr int T = 8192;   // tokens = B*S
static constexpr int D = 1024;
static constexpr int F = 4096;
static constexpr int E = 8;

__device__ __forceinline__ u16 f2b(float f) {
  u32 u = __float_as_uint(f);
  u32 r = (u + 0x7fffu + ((u >> 16) & 1u)) >> 16;  // RNE
  return (u16)r;
}
__device__ __forceinline__ float b2f(u16 u) {
  return __uint_as_float(((u32)u) << 16);
}

// async global->LDS, 16B per lane (m104: dest = wave-uniform base + lane*16)
__device__ __forceinline__ void gload16(const void* g, void* l) {
  typedef const __attribute__((address_space(1))) void* gp_t;
  typedef __attribute__((address_space(3))) void* lp_t;
  __builtin_amdgcn_global_load_lds((gp_t)(uintptr_t)g, (lp_t)(uintptr_t)l, 16, 0, 0);
}

// ---------------- weight transpose + bf16 convert: [E][R][C] -> [E][C][R] ----------------
template<int R, int C>
__global__ void transpose_cvt_kernel(const float* __restrict__ in, u16* __restrict__ outp) {
  __shared__ float tile[64][65];
  const size_t base = (size_t)blockIdx.z * R * C;
  const int r0 = blockIdx.y * 64, c0 = blockIdx.x * 64;
  const int tx = threadIdx.x & 63, tg = threadIdx.x >> 6;
#pragma unroll
  for (int i = 0; i < 16; ++i) {
    int r = i * 4 + tg;
    tile[r][tx] = in[base + (size_t)(r0 + r) * C + (c0 + tx)];
  }
  __syncthreads();
  const int l32 = threadIdx.x & 31, g8 = threadIdx.x >> 5;
#pragma unroll
  for (int i = 0; i < 8; ++i) {
    int rp = i * 8 + g8;
    u16 v0 = f2b(tile[l32 * 2][rp]);
    u16 v1 = f2b(tile[l32 * 2 + 1][rp]);
    *(u32*)(outp + base + (size_t)(c0 + rp) * R + (r0 + l32 * 2)) = (u32)v0 | ((u32)v1 << 16);
  }
}

// ---------------- gate: logits (fp64), top-2, softmax; emits xb. NO atomics. ----------------
__global__ void gate_kernel(const float* __restrict__ x, const float* __restrict__ gw,
                            u16* __restrict__ xb,
                            int* __restrict__ tki, float* __restrict__ tkw) {
  const int lane = threadIdx.x & 63;
  const int t = blockIdx.x * 4 + (threadIdx.x >> 6);
  const float* xr = x + (size_t)t * D + lane * 16;

  float xv[16];
#pragma unroll
  for (int i = 0; i < 4; ++i) {
    float4 v = ((const float4*)xr)[i];
    xv[i * 4 + 0] = v.x; xv[i * 4 + 1] = v.y; xv[i * 4 + 2] = v.z; xv[i * 4 + 3] = v.w;
  }
  union { u16 s[16]; uint4 q[2]; } pk;
#pragma unroll
  for (int j = 0; j < 16; ++j) pk.s[j] = f2b(xv[j]);
  uint4* xbo = (uint4*)(xb + (size_t)t * D + lane * 16);
  xbo[0] = pk.q[0]; xbo[1] = pk.q[1];

  double acc[8] = {0, 0, 0, 0, 0, 0, 0, 0};
  const float4* gwp = (const float4*)(gw + (size_t)(lane * 16) * 8);
#pragma unroll
  for (int j = 0; j < 16; ++j) {
    double xd = (double)xv[j];
    float4 g0 = gwp[j * 2], g1 = gwp[j * 2 + 1];
    acc[0] += xd * (double)g0.x; acc[1] += xd * (double)g0.y;
    acc[2] += xd * (double)g0.z; acc[3] += xd * (double)g0.w;
    acc[4] += xd * (double)g1.x; acc[5] += xd * (double)g1.y;
    acc[6] += xd * (double)g1.z; acc[7] += xd * (double)g1.w;
  }
#pragma unroll
  for (int s = 1; s < 64; s <<= 1) {
#pragma unroll
    for (int e = 0; e < 8; ++e) acc[e] += __shfl_xor(acc[e], s, 64);
  }
  if (lane == 0) {
    int i0 = 0; double l0 = acc[0];
#pragma unroll
    for (int e = 1; e < 8; ++e) if (acc[e] > l0) { l0 = acc[e]; i0 = e; }
    int i1 = -1; double l1 = -1e300;
#pragma unroll
    for (int e = 0; e < 8; ++e) if (e != i0 && acc[e] > l1) { l1 = acc[e]; i1 = e; }
    float w0 = (float)(1.0 / (1.0 + exp(l1 - l0)));  // softmax over {l0,l1}
    float w1f = 1.0f - w0;
    tki[t * 2] = i0; tki[t * 2 + 1] = i1;
    tkw[t * 2] = w0; tkw[t * 2 + 1] = w1f;
  }
}

// ---------------- atomic-free routing: counts + scan + scatter, ONE block ----------------
__global__ __launch_bounds__(1024) void scan_build_kernel(
    const int* __restrict__ tki, const float* __restrict__ tkw,
    int* __restrict__ offs, int* __restrict__ lst, float* __restrict__ lsw) {
  const int tid = threadIdx.x;
  const int lane = tid & 63, wv = tid >> 6;   // 16 waves
  const int base = tid * 16;
  int e_loc[16]; float w_loc[16];
  int cnt[8] = {0, 0, 0, 0, 0, 0, 0, 0};
#pragma unroll
  for (int i = 0; i < 16; ++i) {
    e_loc[i] = tki[base + i];
    w_loc[i] = tkw[base + i];
    cnt[e_loc[i]]++;
  }
  __shared__ int wsum[8][16];
  int excl[8];
#pragma unroll
  for (int e = 0; e < 8; ++e) {
    int inc = cnt[e];
#pragma unroll
    for (int s = 1; s < 64; s <<= 1) {
      int u = __shfl_up(inc, s, 64);
      if (lane >= s) inc += u;
    }
    if (lane == 63) wsum[e][wv] = inc;
    excl[e] = inc - cnt[e];
  }
  __syncthreads();
  int wbase[8], tot[8];
#pragma unroll
  for (int e = 0; e < 8; ++e) {
    int sb = 0, st = 0;
    for (int w = 0; w < 16; ++w) { int v = wsum[e][w]; if (w < wv) sb += v; st += v; }
    wbase[e] = sb; tot[e] = st;
  }
  int eoffs[9]; eoffs[0] = 0;
#pragma unroll
  for (int e = 0; e < 8; ++e) eoffs[e + 1] = eoffs[e] + tot[e];
  if (tid == 0) {
#pragma unroll
    for (int e = 0; e <= 8; ++e) offs[e] = eoffs[e];
  }
  int pos[8];
#pragma unroll
  for (int e = 0; e < 8; ++e) pos[e] = eoffs[e] + wbase[e] + excl[e];
#pragma unroll
  for (int i = 0; i < 16; ++i) {
    int e = e_loc[i];
    int p = pos[e]++;
    lst[p] = (base + i) >> 1;   // token index
    lsw[p] = w_loc[i];
  }
}

// ---------------- grouped GEMM, 256x256, BK=64, 8 waves, m201-faithful 8-phase ----------------
// Pipeline 1.75 tiles deep: at tile-t start, tile t landed + t+1's {A0,B0,B1} in flight
// (6 loads). Per tile: 4 phases x {ds_read; stage 1 half; BARRIER; MFMA(setprio); BARRIER}.
// Stages: ph1 -> A1(t+1) [buf c^1]; ph2,3,4 -> A0,B0,B1(t+2) [buf c!]. WAR-safe because
// each region's reads retire at that phase's post-MFMA barrier before the later-phase
// stage issues; B0 held in regs kills the only same-phase conflict. ONE vmcnt(6) per tile
// (phase 4) retires exactly tile t+1's 8 loads. Tail peels vmcnt(0). T2 swizzle via
// pre-swizzled global source (rule 21). Per-expert XCD chunking (T1).
template<int KD, int ND, bool G1>
__global__ __launch_bounds__(512, 2) void moe_gemm(
    const u16* __restrict__ Abase, const u16* __restrict__ Bt, u16* __restrict__ hOut,
    float* __restrict__ fOut,
    const int* __restrict__ offs, const int* __restrict__ lst,
    const float* __restrict__ lsw) {
  extern __shared__ char smem[];   // A[2][256][128B] @0, B[2][256][128B] @65536
  constexpr int NXT = ND / 256;
  const int e = blockIdx.z;
  const int off = offs[e];
  const int cnt = offs[e + 1] - off;
  const int nmAct = (cnt + 255) >> 8;
  const int act = nmAct * NXT;
  const int d = (int)blockIdx.y * NXT + (int)blockIdx.x;
  const int q8 = (act + 7) >> 3;
  if ((d >> 3) >= q8) return;
  const int lin = (d & 7) * q8 + (d >> 3);
  if (lin >= act) return;
  const int m0 = (lin % nmAct) * 256;
  const int n0 = (lin / nmAct) * 256;
  if (m0 >= cnt) return;

  const int tid = threadIdx.x;
  const int lane = tid & 63;
  const int wave = tid >> 6;
  const int wm = wave >> 2;    // 0..1
  const int wn = wave & 3;     // 0..3

  // staging source byte offsets; group hi covers rows hi*64..hi*64+63
  u32 asrc[4], bsrc[4];
  {
    const int rr = tid >> 3;
    const int cb = (tid & 7) * 16;
#pragma unroll
    for (int hi = 0; hi < 4; ++hi) {
      const int r = hi * 64 + rr;
      const int scb = cb ^ ((r & 7) << 4);  // pre-swizzled source column (rule 21)
      int grow = m0 + r; if (grow >= cnt) grow = cnt - 1;
      u32 arow = G1 ? (u32)lst[off + grow] : (u32)(off + grow);
      asrc[hi] = arow * (u32)(KD * 2) + (u32)scb;
      u32 brow = (u32)e * (u32)ND + (u32)(n0 + r);
      bsrc[hi] = brow * (u32)(KD * 2) + (u32)scb;
    }
  }
  const char* Ac = (const char*)Abase;
  const char* Bc = (const char*)Bt;

  f32x4 acc[4][4][2];
#pragma unroll
  for (int q = 0; q < 4; ++q)
#pragma unroll
    for (int mf = 0; mf < 4; ++mf)
#pragma unroll
      for (int nf = 0; nf < 2; ++nf)
        acc[q][mf][nf] = (f32x4){0.f, 0.f, 0.f, 0.f};

  const u32 ldst = (u32)(tid * 16);
  // A half h: rows h*128..h*128+127 (groups h*2, h*2+1); linear LDS dest
#define STG_A(c, h, kb) do { \
    gload16(Ac + asrc[(h) * 2]     + (kb), smem + ((c) * 32768 + (h) * 16384) + ldst); \
    gload16(Ac + asrc[(h) * 2 + 1] + (kb), smem + ((c) * 32768 + (h) * 16384 + 8192) + ldst); } while (0)
#define STG_B(c, h, kb) do { \
    gload16(Bc + bsrc[(h) * 2]     + (kb), smem + (65536 + (c) * 32768 + (h) * 16384) + ldst); \
    gload16(Bc + bsrc[(h) * 2 + 1] + (kb), smem + (65536 + (c) * 32768 + (h) * 16384 + 8192) + ldst); } while (0)
#define FENCE asm volatile("" ::: "memory")
#define BARRIER do { FENCE; __builtin_amdgcn_s_barrier(); FENCE; } while (0)
#define VMCNT(n) asm volatile("s_waitcnt vmcnt(" #n ")" ::: "memory")
#define SCHED0 __builtin_amdgcn_sched_barrier(0)

  const int arr = wm * 64 + (lane & 15);
  const int brr = wn * 32 + (lane & 15);
  const int koff = (lane >> 4) * 16;

  bf16x8 afr[4][2], b0r[2][2], b1r[2][2];
  auto rdA = [&](int c, int mh) {
#pragma unroll
    for (int mf = 0; mf < 4; ++mf) {
      const int row = mh * 128 + arr + mf * 16;
      const char* p = smem + c * 32768 + row * 128;
      const int sw = (row & 7) << 4;
#pragma unroll
      for (int ks = 0; ks < 2; ++ks)
        afr[mf][ks] = *(const bf16x8*)(p + ((ks * 64 + koff) ^ sw));
    }
  };
  auto rdB = [&](int c, int nh, bf16x8 (&dst)[2][2]) {
#pragma unroll
    for (int nf = 0; nf < 2; ++nf) {
      const int row = nh * 128 + brr + nf * 16;
      const char* p = smem + 65536 + c * 32768 + row * 128;
      const int sw = (row & 7) << 4;
#pragma unroll
      for (int ks = 0; ks < 2; ++ks)
        dst[nf][ks] = *(const bf16x8*)(p + ((ks * 64 + koff) ^ sw));
    }
  };

#define MFMA_Q(q, B) do { \
    __builtin_amdgcn_s_setprio(1); \
    _Pragma("unroll") \
    for (int mf = 0; mf < 4; ++mf) { \
      _Pragma("unroll") \
      for (int nf = 0; nf < 2; ++nf) { \
        _Pragma("unroll") \
        for (int ks = 0; ks < 2; ++ks) \
          acc[q][mf][nf] = __builtin_amdgcn_mfma_f32_16x16x32_bf16(afr[mf][ks], B[nf][ks], acc[q][mf][nf], 0, 0, 0); \
      } \
    } \
    __builtin_amdgcn_s_setprio(0); } while (0)

  constexpr int NT = KD / 64;   // >= 16
  // prologue: tile0 {A0,B0,B1,A1} + tile1 {A0,B0,B1}; vmcnt(6) retires tile0's 8 loads
  STG_A(0, 0, 0); STG_B(0, 0, 0); STG_B(0, 1, 0); STG_A(0, 1, 0);
  STG_A(1, 0, 128); STG_B(1, 0, 128); STG_B(1, 1, 128);
  VMCNT(6);
  BARRIER;

  for (int t = 0; t < NT; ++t) {
    const int c = t & 1;
    const u32 kb1 = (u32)(t + 1) * 128;
    const u32 kb2 = (u32)(t + 2) * 128;
    const bool st1 = (t + 1 < NT);
    const bool st2 = (t + 2 < NT);
    // phase 1: Q0=(A0,B0); stage A1(t+1) -> buf c^1
    rdA(c, 0); rdB(c, 0, b0r);
    if (st1) { STG_A(c ^ 1, 1, kb1); SCHED0; }
    BARRIER;
    MFMA_Q(0, b0r);
    BARRIER;
    // phase 2: Q1=(A0,B1); stage A0(t+2) -> buf c (A0 reads retired at ph1 barrier)
    rdB(c, 1, b1r);
    if (st2) { STG_A(c, 0, kb2); SCHED0; }
    BARRIER;
    MFMA_Q(1, b1r);
    BARRIER;
    // phase 3: Q2=(A1,B1); stage B0(t+2) -> buf c (B0 held in regs since ph1)
    rdA(c, 1);
    if (st2) { STG_B(c, 0, kb2); SCHED0; }
    BARRIER;
    MFMA_Q(2, b1r);
    BARRIER;
    // phase 4: Q3=(A1,B0 held); stage B1(t+2); ONE counted wait per tile
    if (st2) { STG_B(c, 1, kb2); SCHED0; VMCNT(6); }
    else if (st1) { VMCNT(0); }
    BARRIER;
    MFMA_Q(3, b0r);
    BARRIER;
  }

  // epilogue: C/D map col=lane&15, row=(lane>>4)*4+r. Q->(mh,nh): Q0=(0,0) Q1=(0,1) Q2=(1,1) Q3=(1,0)
#pragma unroll
  for (int q = 0; q < 4; ++q) {
    const int mh = q >> 1;
    const int nh = (q == 1 || q == 2) ? 1 : 0;
#pragma unroll
    for (int mf = 0; mf < 4; ++mf) {
#pragma unroll
      for (int r = 0; r < 4; ++r) {
        const int grow = m0 + mh * 128 + wm * 64 + mf * 16 + (lane >> 4) * 4 + r;
        if (grow >= cnt) continue;
        if (G1) {
          u16* op = hOut + (size_t)(off + grow) * ND + n0 + nh * 128 + wn * 32;
#pragma unroll
          for (int nf = 0; nf < 2; ++nf) {
            float v = acc[q][mf][nf][r];
            v = v / (1.f + __expf(-v));   // silu
            op[nf * 16 + (lane & 15)] = f2b(v);
          }
        } else {
          const int tok = lst[off + grow];
          const float wgt = lsw[off + grow];
          float* op = fOut + (size_t)tok * ND + n0 + nh * 128 + wn * 32;
#pragma unroll
          for (int nf = 0; nf < 2; ++nf)
            atomicAdd(op + nf * 16 + (lane & 15), acc[q][mf][nf][r] * wgt);
        }
      }
    }
  }
#undef STG_A
#undef STG_B
#undef FENCE
#undef BARRIER
#undef VMCNT
#undef SCHED0
#undef MFMA_Q
}

extern "C" void kernel_launch(void* const* d_in, const int* in_sizes, int n_in,
                              void* d_out, int out_size, void* d_ws, size_t ws_size,
                              hipStream_t stream) {
  const float* x  = (const float*)d_in[0];
  const float* gw = (const float*)d_in[1];
  const float* w1 = (const float*)d_in[2];
  const float* w2 = (const float*)d_in[3];
  float* outp = (float*)d_out;

  char* ws = (char*)d_ws;
  size_t o = 0;
  auto alloc = [&](size_t b) { size_t r = o; o += (b + 255) & ~(size_t)255; return r; };
  size_t offs_o   = alloc((E + 1) * 4);
  size_t tki_o    = alloc((size_t)T * 2 * 4);
  size_t tkw_o    = alloc((size_t)T * 2 * 4);
  size_t lst_o    = alloc((size_t)T * 2 * 4);
  size_t lsw_o    = alloc((size_t)T * 2 * 4);
  size_t xb_o     = alloc((size_t)T * D * 2);
  size_t w1t_o    = alloc((size_t)E * D * F * 2);
  size_t w2t_o    = alloc((size_t)E * D * F * 2);
  size_t h_o      = alloc((size_t)T * 2 * F * 2);
  if (o > ws_size) {
    fprintf(stderr, "kernel_launch: ws too small (need %zu, have %zu)\n", o, ws_size);
    return;
  }

  int*   offs    = (int*)(ws + offs_o);
  int*   tki     = (int*)(ws + tki_o);
  float* tkw     = (float*)(ws + tkw_o);
  int*   lst     = (int*)(ws + lst_o);
  float* lsw     = (float*)(ws + lsw_o);
  u16*   xb      = (u16*)(ws + xb_o);
  u16*   w1t     = (u16*)(ws + w1t_o);
  u16*   w2t     = (u16*)(ws + w2t_o);
  u16*   h       = (u16*)(ws + h_o);

  hipFuncSetAttribute(reinterpret_cast<const void*>(moe_gemm<D, F, true>),
                      hipFuncAttributeMaxDynamicSharedMemorySize, 131072);
  hipFuncSetAttribute(reinterpret_cast<const void*>(moe_gemm<F, D, false>),
                      hipFuncAttributeMaxDynamicSharedMemorySize, 131072);

  hipMemsetAsync(outp, 0, (size_t)T * D * 4, stream);   // G2 accumulates atomically
  transpose_cvt_kernel<D, F><<<dim3(F / 64, D / 64, E), 256, 0, stream>>>(w1, w1t);
  transpose_cvt_kernel<F, D><<<dim3(D / 64, F / 64, E), 256, 0, stream>>>(w2, w2t);
  gate_kernel<<<T / 4, 256, 0, stream>>>(x, gw, xb, tki, tkw);
  scan_build_kernel<<<1, 1024, 0, stream>>>(tki, tkw, offs, lst, lsw);
  moe_gemm<D, F, true><<<dim3(F / 256, T / 256, E), 512, 131072, stream>>>(
      xb, w1t, h, nullptr, offs, lst, lsw);
  moe_gemm<F, D, false><<<dim3(D / 256, T / 256, E), 512, 131072, stream>>>(
      h, w2t, nullptr, outp, offs, lst, lsw);
}

// Round 10
// 572.896 us; speedup vs baseline: 1.0691x; 1.0691x over previous
//
#include <hip/hip_runtime.h>
#include <cstdio>

typedef unsigned short u16;
typedef unsigned int u32;
typedef __attribute__((ext_vector_type(8))) short bf16x8;
typedef __attribute__((ext_vector_type(4))) float f32x4;

static constexpr int T = 8192;   // tokens = B*S
static constexpr int D = 1024;
static constexpr int F = 4096;
static constexpr int E = 8;

__device__ __forceinline__ u16 f2b(float f) {
  u32 u = __float_as_uint(f);
  u32 r = (u + 0x7fffu + ((u >> 16) & 1u)) >> 16;  // RNE
  return (u16)r;
}
__device__ __forceinline__ float b2f(u16 u) {
  return __uint_as_float(((u32)u) << 16);
}

// async global->LDS, 16B per lane (m104: dest = wave-uniform base + lane*16)
__device__ __forceinline__ void gload16(const void* g, void* l) {
  typedef const __attribute__((address_space(1))) void* gp_t;
  typedef __attribute__((address_space(3))) void* lp_t;
  __builtin_amdgcn_global_load_lds((gp_t)(uintptr_t)g, (lp_t)(uintptr_t)l, 16, 0, 0);
}

// ---------------- weight transpose + bf16 convert: [E][R][C] -> [E][C][R] ----------------
template<int R, int C>
__global__ void transpose_cvt_kernel(const float* __restrict__ in, u16* __restrict__ outp) {
  __shared__ float tile[64][65];
  const size_t base = (size_t)blockIdx.z * R * C;
  const int r0 = blockIdx.y * 64, c0 = blockIdx.x * 64;
  const int tx = threadIdx.x & 63, tg = threadIdx.x >> 6;
#pragma unroll
  for (int i = 0; i < 16; ++i) {
    int r = i * 4 + tg;
    tile[r][tx] = in[base + (size_t)(r0 + r) * C + (c0 + tx)];
  }
  __syncthreads();
  const int l32 = threadIdx.x & 31, g8 = threadIdx.x >> 5;
#pragma unroll
  for (int i = 0; i < 8; ++i) {
    int rp = i * 8 + g8;
    u16 v0 = f2b(tile[l32 * 2][rp]);
    u16 v1 = f2b(tile[l32 * 2 + 1][rp]);
    *(u32*)(outp + base + (size_t)(c0 + rp) * R + (r0 + l32 * 2)) = (u32)v0 | ((u32)v1 << 16);
  }
}

// ---------------- gate: logits (fp64), top-2, softmax; emits xb. NO atomics. ----------------
__global__ void gate_kernel(const float* __restrict__ x, const float* __restrict__ gw,
                            u16* __restrict__ xb,
                            int* __restrict__ tki, float* __restrict__ tkw) {
  const int lane = threadIdx.x & 63;
  const int t = blockIdx.x * 4 + (threadIdx.x >> 6);
  const float* xr = x + (size_t)t * D + lane * 16;

  float xv[16];
#pragma unroll
  for (int i = 0; i < 4; ++i) {
    float4 v = ((const float4*)xr)[i];
    xv[i * 4 + 0] = v.x; xv[i * 4 + 1] = v.y; xv[i * 4 + 2] = v.z; xv[i * 4 + 3] = v.w;
  }
  union { u16 s[16]; uint4 q[2]; } pk;
#pragma unroll
  for (int j = 0; j < 16; ++j) pk.s[j] = f2b(xv[j]);
  uint4* xbo = (uint4*)(xb + (size_t)t * D + lane * 16);
  xbo[0] = pk.q[0]; xbo[1] = pk.q[1];

  double acc[8] = {0, 0, 0, 0, 0, 0, 0, 0};
  const float4* gwp = (const float4*)(gw + (size_t)(lane * 16) * 8);
#pragma unroll
  for (int j = 0; j < 16; ++j) {
    double xd = (double)xv[j];
    float4 g0 = gwp[j * 2], g1 = gwp[j * 2 + 1];
    acc[0] += xd * (double)g0.x; acc[1] += xd * (double)g0.y;
    acc[2] += xd * (double)g0.z; acc[3] += xd * (double)g0.w;
    acc[4] += xd * (double)g1.x; acc[5] += xd * (double)g1.y;
    acc[6] += xd * (double)g1.z; acc[7] += xd * (double)g1.w;
  }
#pragma unroll
  for (int s = 1; s < 64; s <<= 1) {
#pragma unroll
    for (int e = 0; e < 8; ++e) acc[e] += __shfl_xor(acc[e], s, 64);
  }
  if (lane == 0) {
    int i0 = 0; double l0 = acc[0];
#pragma unroll
    for (int e = 1; e < 8; ++e) if (acc[e] > l0) { l0 = acc[e]; i0 = e; }
    int i1 = -1; double l1 = -1e300;
#pragma unroll
    for (int e = 0; e < 8; ++e) if (e != i0 && acc[e] > l1) { l1 = acc[e]; i1 = e; }
    float w0 = (float)(1.0 / (1.0 + exp(l1 - l0)));  // softmax over {l0,l1}
    float w1f = 1.0f - w0;
    tki[t * 2] = i0; tki[t * 2 + 1] = i1;
    tkw[t * 2] = w0; tkw[t * 2 + 1] = w1f;
  }
}

// ---------------- atomic-free routing: counts + scan + scatter, ONE block ----------------
__global__ __launch_bounds__(1024) void scan_build_kernel(
    const int* __restrict__ tki, const float* __restrict__ tkw,
    int* __restrict__ offs, int* __restrict__ lst, float* __restrict__ lsw,
    int* __restrict__ pos_of) {
  const int tid = threadIdx.x;
  const int lane = tid & 63, wv = tid >> 6;   // 16 waves
  const int base = tid * 16;
  int e_loc[16]; float w_loc[16];
  int cnt[8] = {0, 0, 0, 0, 0, 0, 0, 0};
#pragma unroll
  for (int i = 0; i < 16; ++i) {
    e_loc[i] = tki[base + i];
    w_loc[i] = tkw[base + i];
    cnt[e_loc[i]]++;
  }
  __shared__ int wsum[8][16];
  int excl[8];
#pragma unroll
  for (int e = 0; e < 8; ++e) {
    int inc = cnt[e];
#pragma unroll
    for (int s = 1; s < 64; s <<= 1) {
      int u = __shfl_up(inc, s, 64);
      if (lane >= s) inc += u;
    }
    if (lane == 63) wsum[e][wv] = inc;
    excl[e] = inc - cnt[e];
  }
  __syncthreads();
  int wbase[8], tot[8];
#pragma unroll
  for (int e = 0; e < 8; ++e) {
    int sb = 0, st = 0;
    for (int w = 0; w < 16; ++w) { int v = wsum[e][w]; if (w < wv) sb += v; st += v; }
    wbase[e] = sb; tot[e] = st;
  }
  int eoffs[9]; eoffs[0] = 0;
#pragma unroll
  for (int e = 0; e < 8; ++e) eoffs[e + 1] = eoffs[e] + tot[e];
  if (tid == 0) {
#pragma unroll
    for (int e = 0; e <= 8; ++e) offs[e] = eoffs[e];
  }
  int pos[8];
#pragma unroll
  for (int e = 0; e < 8; ++e) pos[e] = eoffs[e] + wbase[e] + excl[e];
#pragma unroll
  for (int i = 0; i < 16; ++i) {
    int e = e_loc[i];
    int p = pos[e]++;
    lst[p] = (base + i) >> 1;   // token index
    lsw[p] = w_loc[i];
    pos_of[base + i] = p;
  }
}

// ---------------- grouped GEMM, 128x256 tile, BK=64, 8 waves — r2 schedule, wider N ----------------
// Same proven single-buffer 2-syncthreads schedule as r2 (best measured), but BN=256:
// A panel reused across 2x N-extent -> 25% less staged L2 traffic per output area.
// LDS 48KB static; __launch_bounds__(512,4) pins regs <=128 -> 2 blocks/CU.
// T2 swizzle via pre-swizzled global source (rule 21). n-major XCD chunking (T1, r7 win).
// G1: silu -> bf16 h. G2: bf16 y scaled by lsw (combine kernel adds pairs; r2 evidence
// that atomic-fp32 epilogue costs ~15-20us/dispatch).
template<int KD, int ND, bool G1>
__global__ __launch_bounds__(512, 4) void moe_gemm(
    const u16* __restrict__ Abase, const u16* __restrict__ Bt, u16* __restrict__ Out,
    const int* __restrict__ offs, const int* __restrict__ lst,
    const float* __restrict__ lsw) {
  __shared__ u16 As[128 * 64];   // 16 KB
  __shared__ u16 Bs[256 * 64];   // 32 KB
  constexpr int NXT = ND / 256;
  const int e = blockIdx.z;
  const int off = offs[e];
  const int cnt = offs[e + 1] - off;
  const int nmAct = (cnt + 127) >> 7;
  const int act = nmAct * NXT;
  const int d = (int)blockIdx.y * NXT + (int)blockIdx.x;
  const int q8 = (act + 7) >> 3;
  if ((d >> 3) >= q8) return;
  const int lin = (d & 7) * q8 + (d >> 3);
  if (lin >= act) return;
  const int m0 = (lin % nmAct) * 128;   // n-major: XCD-neighbors share n0 (B-slice L2-resident)
  const int n0 = (lin / nmAct) * 256;
  if (m0 >= cnt) return;

  const int tid = threadIdx.x;
  const int lane = tid & 63;
  const int wave = tid >> 6;
  const int wm = wave >> 2;     // 0..1 : 64-row half of the 128-row tile
  const int wn = wave & 3;      // 0..3 : 64-col quarter of the 256-col tile

  // staging source byte offsets (pre-swizzled columns, rule 21); 512 thr x 16B = 8KB/instr
  u32 asrc[2], bsrc[4];
  {
    const int rr = tid >> 3;          // 0..63
    const int cb = (tid & 7) * 16;
#pragma unroll
    for (int i = 0; i < 2; ++i) {
      const int row = i * 64 + rr;    // A rows 0..127
      const int scb = cb ^ ((row & 7) << 4);
      int grow = m0 + row; if (grow >= cnt) grow = cnt - 1;
      u32 arow = G1 ? (u32)lst[off + grow] : (u32)(off + grow);
      asrc[i] = arow * (u32)(KD * 2) + (u32)scb;
    }
#pragma unroll
    for (int i = 0; i < 4; ++i) {
      const int row = i * 64 + rr;    // B rows 0..255
      const int scb = cb ^ ((row & 7) << 4);
      u32 brow = (u32)e * (u32)ND + (u32)(n0 + row);
      bsrc[i] = brow * (u32)(KD * 2) + (u32)scb;
    }
  }
  const char* Ac = (const char*)Abase;
  const char* Bc = (const char*)Bt;

  f32x4 acc[4][4];
#pragma unroll
  for (int i = 0; i < 4; ++i)
#pragma unroll
    for (int j = 0; j < 4; ++j) acc[i][j] = (f32x4){0.f, 0.f, 0.f, 0.f};

  const int arow_r = wm * 64 + (lane & 15);
  const int brow_r = wn * 64 + (lane & 15);
  const int koff = (lane >> 4) * 16;

  for (int kt = 0; kt < KD / 64; ++kt) {
    const u32 kb = (u32)kt * 128;   // 64 bf16 = 128 bytes
    __syncthreads();
#pragma unroll
    for (int i = 0; i < 2; ++i)
      gload16(Ac + asrc[i] + kb, (char*)As + i * 8192 + tid * 16);
#pragma unroll
    for (int i = 0; i < 4; ++i)
      gload16(Bc + bsrc[i] + kb, (char*)Bs + i * 8192 + tid * 16);
    __syncthreads();
#pragma unroll
    for (int ks = 0; ks < 2; ++ks) {
      const int kbyte = ks * 64 + koff;
      bf16x8 af[4], bfv[4];
#pragma unroll
      for (int mf = 0; mf < 4; ++mf) {
        const int row = arow_r + mf * 16;
        af[mf] = *(const bf16x8*)((const char*)As + row * 128 + (kbyte ^ ((row & 7) << 4)));
      }
#pragma unroll
      for (int nf = 0; nf < 4; ++nf) {
        const int row = brow_r + nf * 16;
        bfv[nf] = *(const bf16x8*)((const char*)Bs + row * 128 + (kbyte ^ ((row & 7) << 4)));
      }
#pragma unroll
      for (int mf = 0; mf < 4; ++mf)
#pragma unroll
        for (int nf = 0; nf < 4; ++nf)
          acc[mf][nf] = __builtin_amdgcn_mfma_f32_16x16x32_bf16(af[mf], bfv[nf], acc[mf][nf], 0, 0, 0);
    }
  }

  // epilogue: C/D map col=lane&15, row=(lane>>4)*4+r
#pragma unroll
  for (int mf = 0; mf < 4; ++mf) {
#pragma unroll
    for (int r = 0; r < 4; ++r) {
      const int grow = m0 + wm * 64 + mf * 16 + (lane >> 4) * 4 + r;
      if (grow >= cnt) continue;
      const float wgt = G1 ? 1.f : lsw[off + grow];
      u16* op = Out + (size_t)(off + grow) * ND + n0 + wn * 64;
#pragma unroll
      for (int nf = 0; nf < 4; ++nf) {
        float v = acc[mf][nf][r];
        if (G1) v = v / (1.f + __expf(-v));   // silu
        else v *= wgt;
        op[nf * 16 + (lane & 15)] = f2b(v);
      }
    }
  }
}

// ---------------- final combine: out[t] = y[pos0[t]] + y[pos1[t]] ----------------
__global__ void combine_kernel(const u16* __restrict__ y, const int* __restrict__ pos_of,
                               float* __restrict__ outp) {
  int idx = blockIdx.x * 256 + threadIdx.x;   // T*D/8 threads
  int t = idx >> 7;                           // D/8 = 128 chunks per token
  int c = (idx & 127) * 8;
  int p0 = pos_of[t * 2], p1 = pos_of[t * 2 + 1];
  union { uint4 v; u16 s[8]; } a, b;
  a.v = *(const uint4*)(y + (size_t)p0 * D + c);
  b.v = *(const uint4*)(y + (size_t)p1 * D + c);
  float4 r0, r1;
  r0.x = b2f(a.s[0]) + b2f(b.s[0]); r0.y = b2f(a.s[1]) + b2f(b.s[1]);
  r0.z = b2f(a.s[2]) + b2f(b.s[2]); r0.w = b2f(a.s[3]) + b2f(b.s[3]);
  r1.x = b2f(a.s[4]) + b2f(b.s[4]); r1.y = b2f(a.s[5]) + b2f(b.s[5]);
  r1.z = b2f(a.s[6]) + b2f(b.s[6]); r1.w = b2f(a.s[7]) + b2f(b.s[7]);
  *(float4*)(outp + (size_t)t * D + c) = r0;
  *(float4*)(outp + (size_t)t * D + c + 4) = r1;
}

extern "C" void kernel_launch(void* const* d_in, const int* in_sizes, int n_in,
                              void* d_out, int out_size, void* d_ws, size_t ws_size,
                              hipStream_t stream) {
  const float* x  = (const float*)d_in[0];
  const float* gw = (const float*)d_in[1];
  const float* w1 = (const float*)d_in[2];
  const float* w2 = (const float*)d_in[3];
  float* outp = (float*)d_out;

  char* ws = (char*)d_ws;
  size_t o = 0;
  auto alloc = [&](size_t b) { size_t r = o; o += (b + 255) & ~(size_t)255; return r; };
  size_t offs_o   = alloc((E + 1) * 4);
  size_t tki_o    = alloc((size_t)T * 2 * 4);
  size_t tkw_o    = alloc((size_t)T * 2 * 4);
  size_t lst_o    = alloc((size_t)T * 2 * 4);
  size_t lsw_o    = alloc((size_t)T * 2 * 4);
  size_t pos_o    = alloc((size_t)T * 2 * 4);
  size_t xb_o     = alloc((size_t)T * D * 2);
  size_t w1t_o    = alloc((size_t)E * D * F * 2);
  size_t w2t_o    = alloc((size_t)E * D * F * 2);
  size_t h_o      = alloc((size_t)T * 2 * F * 2);
  size_t y_o      = alloc((size_t)T * 2 * D * 2);
  if (o > ws_size) {
    fprintf(stderr, "kernel_launch: ws too small (need %zu, have %zu)\n", o, ws_size);
    return;
  }

  int*   offs    = (int*)(ws + offs_o);
  int*   tki     = (int*)(ws + tki_o);
  float* tkw     = (float*)(ws + tkw_o);
  int*   lst     = (int*)(ws + lst_o);
  float* lsw     = (float*)(ws + lsw_o);
  int*   pos_of  = (int*)(ws + pos_o);
  u16*   xb      = (u16*)(ws + xb_o);
  u16*   w1t     = (u16*)(ws + w1t_o);
  u16*   w2t     = (u16*)(ws + w2t_o);
  u16*   h       = (u16*)(ws + h_o);
  u16*   y       = (u16*)(ws + y_o);

  transpose_cvt_kernel<D, F><<<dim3(F / 64, D / 64, E), 256, 0, stream>>>(w1, w1t);
  transpose_cvt_kernel<F, D><<<dim3(D / 64, F / 64, E), 256, 0, stream>>>(w2, w2t);
  gate_kernel<<<T / 4, 256, 0, stream>>>(x, gw, xb, tki, tkw);
  scan_build_kernel<<<1, 1024, 0, stream>>>(tki, tkw, offs, lst, lsw, pos_of);
  moe_gemm<D, F, true><<<dim3(F / 256, T / 128, E), 512, 0, stream>>>(
      xb, w1t, h, offs, lst, lsw);
  moe_gemm<F, D, false><<<dim3(D / 256, T / 128, E), 512, 0, stream>>>(
      h, w2t, y, offs, lst, lsw);
  combine_kernel<<<T * D / 8 / 256, 256, 0, stream>>>(y, pos_of, outp);
}

// Round 11
// 549.086 us; speedup vs baseline: 1.1155x; 1.0434x over previous
//
#include <hip/hip_runtime.h>
#include <cstdio>

typedef unsigned short u16;
typedef unsigned int u32;
typedef __attribute__((ext_vector_type(8))) short bf16x8;
typedef __attribute__((ext_vector_type(4))) float f32x4;

static constexpr int T = 8192;   // tokens = B*S
static constexpr int D = 1024;
static constexpr int F = 4096;
static constexpr int E = 8;

__device__ __forceinline__ u16 f2b(float f) {
  u32 u = __float_as_uint(f);
  u32 r = (u + 0x7fffu + ((u >> 16) & 1u)) >> 16;  // RNE
  return (u16)r;
}
__device__ __forceinline__ float b2f(u16 u) {
  return __uint_as_float(((u32)u) << 16);
}

// async global->LDS, 16B per lane (m104: dest = wave-uniform base + lane*16)
__device__ __forceinline__ void gload16(const void* g, void* l) {
  typedef const __attribute__((address_space(1))) void* gp_t;
  typedef __attribute__((address_space(3))) void* lp_t;
  __builtin_amdgcn_global_load_lds((gp_t)(uintptr_t)g, (lp_t)(uintptr_t)l, 16, 0, 0);
}

// ---------------- weight transpose + bf16 convert: [E][R][C] -> [E][C][R] ----------------
template<int R, int C>
__global__ void transpose_cvt_kernel(const float* __restrict__ in, u16* __restrict__ outp) {
  __shared__ float tile[64][65];
  const size_t base = (size_t)blockIdx.z * R * C;
  const int r0 = blockIdx.y * 64, c0 = blockIdx.x * 64;
  const int tx = threadIdx.x & 63, tg = threadIdx.x >> 6;
#pragma unroll
  for (int i = 0; i < 16; ++i) {
    int r = i * 4 + tg;
    tile[r][tx] = in[base + (size_t)(r0 + r) * C + (c0 + tx)];
  }
  __syncthreads();
  const int l32 = threadIdx.x & 31, g8 = threadIdx.x >> 5;
#pragma unroll
  for (int i = 0; i < 8; ++i) {
    int rp = i * 8 + g8;
    u16 v0 = f2b(tile[l32 * 2][rp]);
    u16 v1 = f2b(tile[l32 * 2 + 1][rp]);
    *(u32*)(outp + base + (size_t)(c0 + rp) * R + (r0 + l32 * 2)) = (u32)v0 | ((u32)v1 << 16);
  }
}

// ---------------- gate: logits (fp64), top-2, softmax; emits xb. NO atomics. ----------------
__global__ void gate_kernel(const float* __restrict__ x, const float* __restrict__ gw,
                            u16* __restrict__ xb,
                            int* __restrict__ tki, float* __restrict__ tkw) {
  const int lane = threadIdx.x & 63;
  const int t = blockIdx.x * 4 + (threadIdx.x >> 6);
  const float* xr = x + (size_t)t * D + lane * 16;

  float xv[16];
#pragma unroll
  for (int i = 0; i < 4; ++i) {
    float4 v = ((const float4*)xr)[i];
    xv[i * 4 + 0] = v.x; xv[i * 4 + 1] = v.y; xv[i * 4 + 2] = v.z; xv[i * 4 + 3] = v.w;
  }
  union { u16 s[16]; uint4 q[2]; } pk;
#pragma unroll
  for (int j = 0; j < 16; ++j) pk.s[j] = f2b(xv[j]);
  uint4* xbo = (uint4*)(xb + (size_t)t * D + lane * 16);
  xbo[0] = pk.q[0]; xbo[1] = pk.q[1];

  double acc[8] = {0, 0, 0, 0, 0, 0, 0, 0};
  const float4* gwp = (const float4*)(gw + (size_t)(lane * 16) * 8);
#pragma unroll
  for (int j = 0; j < 16; ++j) {
    double xd = (double)xv[j];
    float4 g0 = gwp[j * 2], g1 = gwp[j * 2 + 1];
    acc[0] += xd * (double)g0.x; acc[1] += xd * (double)g0.y;
    acc[2] += xd * (double)g0.z; acc[3] += xd * (double)g0.w;
    acc[4] += xd * (double)g1.x; acc[5] += xd * (double)g1.y;
    acc[6] += xd * (double)g1.z; acc[7] += xd * (double)g1.w;
  }
#pragma unroll
  for (int s = 1; s < 64; s <<= 1) {
#pragma unroll
    for (int e = 0; e < 8; ++e) acc[e] += __shfl_xor(acc[e], s, 64);
  }
  if (lane == 0) {
    int i0 = 0; double l0 = acc[0];
#pragma unroll
    for (int e = 1; e < 8; ++e) if (acc[e] > l0) { l0 = acc[e]; i0 = e; }
    int i1 = -1; double l1 = -1e300;
#pragma unroll
    for (int e = 0; e < 8; ++e) if (e != i0 && acc[e] > l1) { l1 = acc[e]; i1 = e; }
    float w0 = (float)(1.0 / (1.0 + exp(l1 - l0)));  // softmax over {l0,l1}
    float w1f = 1.0f - w0;
    tki[t * 2] = i0; tki[t * 2 + 1] = i1;
    tkw[t * 2] = w0; tkw[t * 2 + 1] = w1f;
  }
}

// ---------------- atomic-free routing: counts + scan + scatter, ONE block ----------------
__global__ __launch_bounds__(1024) void scan_build_kernel(
    const int* __restrict__ tki, const float* __restrict__ tkw,
    int* __restrict__ offs, int* __restrict__ lst, float* __restrict__ lsw) {
  const int tid = threadIdx.x;
  const int lane = tid & 63, wv = tid >> 6;   // 16 waves
  const int base = tid * 16;
  int e_loc[16]; float w_loc[16];
  int cnt[8] = {0, 0, 0, 0, 0, 0, 0, 0};
#pragma unroll
  for (int i = 0; i < 16; ++i) {
    e_loc[i] = tki[base + i];
    w_loc[i] = tkw[base + i];
    cnt[e_loc[i]]++;
  }
  __shared__ int wsum[8][16];
  int excl[8];
#pragma unroll
  for (int e = 0; e < 8; ++e) {
    int inc = cnt[e];
#pragma unroll
    for (int s = 1; s < 64; s <<= 1) {
      int u = __shfl_up(inc, s, 64);
      if (lane >= s) inc += u;
    }
    if (lane == 63) wsum[e][wv] = inc;
    excl[e] = inc - cnt[e];
  }
  __syncthreads();
  int wbase[8], tot[8];
#pragma unroll
  for (int e = 0; e < 8; ++e) {
    int sb = 0, st = 0;
    for (int w = 0; w < 16; ++w) { int v = wsum[e][w]; if (w < wv) sb += v; st += v; }
    wbase[e] = sb; tot[e] = st;
  }
  int eoffs[9]; eoffs[0] = 0;
#pragma unroll
  for (int e = 0; e < 8; ++e) eoffs[e + 1] = eoffs[e] + tot[e];
  if (tid == 0) {
#pragma unroll
    for (int e = 0; e <= 8; ++e) offs[e] = eoffs[e];
  }
  int pos[8];
#pragma unroll
  for (int e = 0; e < 8; ++e) pos[e] = eoffs[e] + wbase[e] + excl[e];
#pragma unroll
  for (int i = 0; i < 16; ++i) {
    int e = e_loc[i];
    int p = pos[e]++;
    lst[p] = (base + i) >> 1;   // token index
    lsw[p] = w_loc[i];
  }
}

// ---------------- grouped GEMM, 128x128, BK=64, 4 waves — r2 schedule + XCD chunk + fused G2 ----------------
// Single-buffer, two __syncthreads per K-tile (best measured). global_load_lds staging,
// pre-swizzled global source + swizzled ds_read (T2, rule 21). n-major XCD chunking (T1).
// G1: silu -> bf16 h. G2(!G1): atomicAdd fp32 into out rows scattered by lst (combine fused,
// best measured total: r8=543 vs r10=572).
template<int KD, int ND, bool G1>
__global__ __launch_bounds__(256, 2) void moe_gemm(
    const u16* __restrict__ Abase, const u16* __restrict__ Bt, u16* __restrict__ hOut,
    float* __restrict__ fOut,
    const int* __restrict__ offs, const int* __restrict__ lst,
    const float* __restrict__ lsw) {
  __shared__ u16 As[128 * 64];
  __shared__ u16 Bs[128 * 64];
  constexpr int NXT = ND / 128;
  const int e = blockIdx.z;
  const int off = offs[e];
  const int cnt = offs[e + 1] - off;
  const int nmAct = (cnt + 127) >> 7;
  const int act = nmAct * NXT;
  const int d = (int)blockIdx.y * NXT + (int)blockIdx.x;
  const int q8 = (act + 7) >> 3;
  if ((d >> 3) >= q8) return;
  const int lin = (d & 7) * q8 + (d >> 3);
  if (lin >= act) return;
  const int m0 = (lin % nmAct) * 128;   // n-major: XCD-neighbors share n0 (B-slice L2-resident)
  const int n0 = (lin / nmAct) * 128;
  if (m0 >= cnt) return;

  const int tid = threadIdx.x;
  const int lane = tid & 63;
  const int wave = tid >> 6;
  const int wm = wave >> 1;     // 0..1
  const int wn = wave & 1;      // 0..1

  // staging source byte offsets (pre-swizzled columns, rule 21)
  u32 asrc[4], bsrc[4];
#pragma unroll
  for (int i = 0; i < 4; ++i) {
    const int linear = i * 256 + tid;
    const int row = linear >> 3;          // 0..127
    const int cb = (linear & 7) * 16;
    const int scb = cb ^ ((row & 7) << 4);
    int grow = m0 + row; if (grow >= cnt) grow = cnt - 1;
    u32 arow = G1 ? (u32)lst[off + grow] : (u32)(off + grow);
    asrc[i] = arow * (u32)(KD * 2) + (u32)scb;
    u32 brow = (u32)e * (u32)ND + (u32)(n0 + row);
    bsrc[i] = brow * (u32)(KD * 2) + (u32)scb;
  }
  const char* Ac = (const char*)Abase;
  const char* Bc = (const char*)Bt;

  f32x4 acc[4][4];
#pragma unroll
  for (int i = 0; i < 4; ++i)
#pragma unroll
    for (int j = 0; j < 4; ++j) acc[i][j] = (f32x4){0.f, 0.f, 0.f, 0.f};

  const int arow_r = wm * 64 + (lane & 15);
  const int brow_r = wn * 64 + (lane & 15);
  const int koff = (lane >> 4) * 16;

  for (int kt = 0; kt < KD / 64; ++kt) {
    const u32 kb = (u32)kt * 128;   // 64 bf16 = 128 bytes
    __syncthreads();
#pragma unroll
    for (int i = 0; i < 4; ++i) {
      gload16(Ac + asrc[i] + kb, (char*)As + i * 4096 + tid * 16);
      gload16(Bc + bsrc[i] + kb, (char*)Bs + i * 4096 + tid * 16);
    }
    __syncthreads();
#pragma unroll
    for (int ks = 0; ks < 2; ++ks) {
      const int kbyte = ks * 64 + koff;
      bf16x8 af[4], bfv[4];
#pragma unroll
      for (int mf = 0; mf < 4; ++mf) {
        const int row = arow_r + mf * 16;
        af[mf] = *(const bf16x8*)((const char*)As + row * 128 + (kbyte ^ ((row & 7) << 4)));
      }
#pragma unroll
      for (int nf = 0; nf < 4; ++nf) {
        const int row = brow_r + nf * 16;
        bfv[nf] = *(const bf16x8*)((const char*)Bs + row * 128 + (kbyte ^ ((row & 7) << 4)));
      }
#pragma unroll
      for (int mf = 0; mf < 4; ++mf)
#pragma unroll
        for (int nf = 0; nf < 4; ++nf)
          acc[mf][nf] = __builtin_amdgcn_mfma_f32_16x16x32_bf16(af[mf], bfv[nf], acc[mf][nf], 0, 0, 0);
    }
  }

  // epilogue: C/D map col=lane&15, row=(lane>>4)*4+r
#pragma unroll
  for (int mf = 0; mf < 4; ++mf) {
#pragma unroll
    for (int r = 0; r < 4; ++r) {
      const int grow = m0 + wm * 64 + mf * 16 + (lane >> 4) * 4 + r;
      if (grow >= cnt) continue;
      if (G1) {
        u16* op = hOut + (size_t)(off + grow) * ND + n0 + wn * 64;
#pragma unroll
        for (int nf = 0; nf < 4; ++nf) {
          float v = acc[mf][nf][r];
          v = v / (1.f + __expf(-v));   // silu
          op[nf * 16 + (lane & 15)] = f2b(v);
        }
      } else {
        const int tok = lst[off + grow];
        const float wgt = lsw[off + grow];
        float* op = fOut + (size_t)tok * ND + n0 + wn * 64;
#pragma unroll
        for (int nf = 0; nf < 4; ++nf)
          atomicAdd(op + nf * 16 + (lane & 15), acc[mf][nf][r] * wgt);
      }
    }
  }
}

extern "C" void kernel_launch(void* const* d_in, const int* in_sizes, int n_in,
                              void* d_out, int out_size, void* d_ws, size_t ws_size,
                              hipStream_t stream) {
  const float* x  = (const float*)d_in[0];
  const float* gw = (const float*)d_in[1];
  const float* w1 = (const float*)d_in[2];
  const float* w2 = (const float*)d_in[3];
  float* outp = (float*)d_out;

  char* ws = (char*)d_ws;
  size_t o = 0;
  auto alloc = [&](size_t b) { size_t r = o; o += (b + 255) & ~(size_t)255; return r; };
  size_t offs_o   = alloc((E + 1) * 4);
  size_t tki_o    = alloc((size_t)T * 2 * 4);
  size_t tkw_o    = alloc((size_t)T * 2 * 4);
  size_t lst_o    = alloc((size_t)T * 2 * 4);
  size_t lsw_o    = alloc((size_t)T * 2 * 4);
  size_t xb_o     = alloc((size_t)T * D * 2);
  size_t w1t_o    = alloc((size_t)E * D * F * 2);
  size_t w2t_o    = alloc((size_t)E * D * F * 2);
  size_t h_o      = alloc((size_t)T * 2 * F * 2);
  if (o > ws_size) {
    fprintf(stderr, "kernel_launch: ws too small (need %zu, have %zu)\n", o, ws_size);
    return;
  }

  int*   offs    = (int*)(ws + offs_o);
  int*   tki     = (int*)(ws + tki_o);
  float* tkw     = (float*)(ws + tkw_o);
  int*   lst     = (int*)(ws + lst_o);
  float* lsw     = (float*)(ws + lsw_o);
  u16*   xb      = (u16*)(ws + xb_o);
  u16*   w1t     = (u16*)(ws + w1t_o);
  u16*   w2t     = (u16*)(ws + w2t_o);
  u16*   h       = (u16*)(ws + h_o);

  hipMemsetAsync(outp, 0, (size_t)T * D * 4, stream);   // G2 accumulates atomically
  transpose_cvt_kernel<D, F><<<dim3(F / 64, D / 64, E), 256, 0, stream>>>(w1, w1t);
  transpose_cvt_kernel<F, D><<<dim3(D / 64, F / 64, E), 256, 0, stream>>>(w2, w2t);
  gate_kernel<<<T / 4, 256, 0, stream>>>(x, gw, xb, tki, tkw);
  scan_build_kernel<<<1, 1024, 0, stream>>>(tki, tkw, offs, lst, lsw);
  moe_gemm<D, F, true><<<dim3(F / 128, T / 128, E), 256, 0, stream>>>(
      xb, w1t, h, nullptr, offs, lst, lsw);
  moe_gemm<F, D, false><<<dim3(D / 128, T / 128, E), 256, 0, stream>>>(
      h, w2t, nullptr, outp, offs, lst, lsw);
}